// Round 12
// baseline (15350.963 us; speedup 1.0000x reference)
//
#include <hip/hip_runtime.h>

typedef short bf16x8 __attribute__((ext_vector_type(8)));
typedef float f32x4  __attribute__((ext_vector_type(4)));
typedef unsigned long long u64;

#define MFMA16(a, b, c) __builtin_amdgcn_mfma_f32_16x16x32_bf16((a), (b), (c), 0, 0, 0)
#define AT_LD(p, o)    __hip_atomic_load((p), (o), __HIP_MEMORY_SCOPE_AGENT)
#define AT_ST(p, v, o) __hip_atomic_store((p), (v), (o), __HIP_MEMORY_SCOPE_AGENT)
#define AT_ADD(p, v, o) __hip_atomic_fetch_add((p), (v), (o), __HIP_MEMORY_SCOPE_AGENT)
#define WG_LD(p) __hip_atomic_load((p), __ATOMIC_RELAXED, __HIP_MEMORY_SCOPE_WORKGROUP)
#define WG_ST(p, v) __hip_atomic_store((p), (v), __ATOMIC_RELAXED, __HIP_MEMORY_SCOPE_WORKGROUP)

#define HSLOT 67584      // h ring slot stride in bf16 elems (128KB + 4KB pad)

// barrier zone (words): flags[wg]=wg*64 (0..4032, 64 wgs), gemm tree 8256(cnt)/8320(gen),
// gemm_done=8384, rec_done=8448
__device__ __forceinline__ unsigned short f2bf(float f) {
  union { float f; unsigned u; } v; v.f = f;
  unsigned u = v.u;
  u += 0x7fffu + ((u >> 16) & 1u);
  return (unsigned short)(u >> 16);
}
__device__ __forceinline__ float bf2f(unsigned short h) {
  union { unsigned u; float f; } v; v.u = ((unsigned)h) << 16;
  return v.f;
}
__device__ __forceinline__ float sigf(float x) { return 1.f / (1.f + __expf(-x)); }
__device__ __forceinline__ float tanh_(float x) {
  x = fminf(15.f, fmaxf(-15.f, x));
  float e = __expf(2.f * x);
  return (e - 1.f) / (e + 1.f);
}

// ---- per-chunk release barrier for the 128 GEMM wgs ----
__device__ __forceinline__ void gbar_gemm(unsigned* bar, unsigned target) {
  __syncthreads();
  if (threadIdx.x == 0) {
    unsigned arr = AT_ADD(bar + 8256, 1u, __ATOMIC_RELEASE);  // vmcnt drain + L2 wb
    if (arr == target * 128u - 1u) AT_ST(bar + 8320, target, __ATOMIC_RELEASE);
    while (AT_LD(bar + 8320, __ATOMIC_RELAXED) < target) __builtin_amdgcn_s_sleep(4);
    asm volatile("" ::: "memory");
  }
  __syncthreads();
}

// ---------------- weight conversion fp32 -> bf16 ----------------
__global__ void k_conv(const float* __restrict__ wih, const float* __restrict__ whh,
                       const float* __restrict__ wemb,
                       unsigned short* __restrict__ oih, unsigned short* __restrict__ ohh,
                       unsigned short* __restrict__ oemb) {
  const size_t NIH = (size_t)4096 * 512, NHH = (size_t)4096 * 1024;
  const size_t NE = (size_t)32000 * 512;
  size_t i0 = ((size_t)blockIdx.x * blockDim.x + threadIdx.x) * 4;
  size_t gs = (size_t)gridDim.x * blockDim.x * 4;
  for (size_t j = i0; j < NIH; j += gs) {
    float4 v = *(const float4*)(wih + j);
    uint2 pk;
    pk.x = (unsigned)f2bf(v.x) | ((unsigned)f2bf(v.y) << 16);
    pk.y = (unsigned)f2bf(v.z) | ((unsigned)f2bf(v.w) << 16);
    *(uint2*)(oih + j) = pk;
  }
  for (size_t j = i0; j < NHH; j += gs) {
    float4 v = *(const float4*)(whh + j);
    uint2 pk;
    pk.x = (unsigned)f2bf(v.x) | ((unsigned)f2bf(v.y) << 16);
    pk.y = (unsigned)f2bf(v.z) | ((unsigned)f2bf(v.w) << 16);
    *(uint2*)(ohh + j) = pk;
  }
  if (oemb)
    for (size_t j = i0; j < NE; j += gs) {
      float4 v = *(const float4*)(wemb + j);
      uint2 pk;
      pk.x = (unsigned)f2bf(v.x) | ((unsigned)f2bf(v.y) << 16);
      pk.y = (unsigned)f2bf(v.z) | ((unsigned)f2bf(v.w) << 16);
      *(uint2*)(oemb + j) = pk;
    }
}

// ---------------- lengths / selection index ----------------
__global__ void k_tsel(const int* __restrict__ x, int* __restrict__ tsel,
                       int* __restrict__ padsel) {
  int b = threadIdx.x >> 3, j = threadIdx.x & 7;
  int c = 0;
  for (int t = j * 64; t < j * 64 + 64; ++t) c += (x[b * 512 + t] != 1) ? 1 : 0;
  c += __shfl_xor(c, 1);
  c += __shfl_xor(c, 2);
  c += __shfl_xor(c, 4);
  if (j == 0) {
    int ts = (c - 1) & 511;                        // len==0 wraps to T-1
    tsel[b] = ts;
    padsel[b] = (x[b * 512 + ts] == 1) ? 1 : 0;
  }
}

// ---------------- final logits: [64,1024] @ [8,1024]^T + b ----------------
__global__ void k_logits(const float* __restrict__ finalb, const float* __restrict__ Wout,
                         const float* __restrict__ bout, float* __restrict__ out) {
  int tid = threadIdx.x;
  for (int e = tid; e < 512; e += 256) {
    int b = e >> 3, o = e & 7;
    const float* f = finalb + (size_t)b * 1024;
    const float* w = Wout + (size_t)o * 1024;
    float s = 0.f;
    for (int k = 0; k < 1024; ++k) s += f[k] * w[k];
    out[e] = s + bout[o];
  }
}

// ---------------- main kernel: 192 wgs = 64 rec (16 cols each) + 128 GEMM ----------------
struct SmemT {
  unsigned tok;                                      // rec: barrier token (LDS)
  union {
    struct {
      unsigned short sW[64][1024];                   // W_hh slice: 64 z-rows x K=1024
      float z[64][68];                               // z exchange: [b][zrow 0..63]
    } rec;
    struct { unsigned short A[128][72]; unsigned short Bt[256][72]; } g;
    struct { unsigned short zs[128][136]; } zst;
  } u;
};

__global__ __launch_bounds__(256, 1) void k_main(
    const int* __restrict__ x, const float* __restrict__ Wemb,
    const float* __restrict__ bih, const float* __restrict__ bhh,
    const unsigned short* __restrict__ Wihb, const unsigned short* __restrict__ Whhb,
    const unsigned short* __restrict__ wembb,
    unsigned short* __restrict__ hr, float* __restrict__ finalb,
    const int* __restrict__ tsel, const int* __restrict__ padsel,
    unsigned short* __restrict__ zxr, unsigned* __restrict__ bar, int chunkT,
    int nslot) {
  __shared__ SmemT smem;
  const int wg = blockIdx.x, tid = threadIdx.x;
  const int wave = tid >> 6, lane = tid & 63;
  const int l15 = lane & 15, lg = lane >> 4;
  unsigned* gemm_done = bar + 8384;
  unsigned* rec_done  = bar + 8448;
  const f32x4 fz = {0.f, 0.f, 0.f, 0.f};
  const int nChunks = 512 / chunkT;
  const size_t slotE = (size_t)chunkT * 64 * 4096;

  if (wg < 64) {
    // ================= RECURRENT ROLE: 16 h-cols, 64 z-rows =================
    if (tid == 0) smem.tok = 0;
    // sW fill: z-row r -> global W row (r>>4)*1024 + wg*16 + (r&15)
    for (int e = tid; e < 64 * 128; e += 256) {
      int r = e >> 7, kq = (e & 127) << 3;
      int grow = (r >> 4) * 1024 + wg * 16 + (r & 15);
      *(uint4*)&smem.u.rec.sW[r][kq] = *(const uint4*)(Whhb + (size_t)grow * 1024 + kq);
    }
    const int q = tid & 3;
    const int my_b = tid >> 2;
    const int c0 = wg * 16 + 4 * q;                  // first of this thread's 4 cols
    float biasv[4][4];                               // [i][g]
#pragma unroll
    for (int i = 0; i < 4; ++i)
#pragma unroll
      for (int g = 0; g < 4; ++g)
        biasv[i][g] = bih[g * 1024 + c0 + i] + bhh[g * 1024 + c0 + i];
    const int my_tsel = tsel[my_b];
    const int my_pad = padsel[my_b];
    // frag-order store: k = c0 + i (i=0..3 contiguous within k&7): one u64 store
    const size_t hwe = (size_t)(my_b >> 4) * 16384 + (size_t)(wg >> 1) * 512 +
                       (size_t)((wg * 2 + (q >> 1)) & 3) * 128 +
                       (size_t)(my_b & 15) * 8 + (size_t)(q & 1) * 4;
    float cc0 = 0.f, cc1 = 0.f, cc2 = 0.f, cc3 = 0.f;

    // zero h slot 0 (64 wg x 256 thr x 8B = 128KB); flag=1 means "h_0 visible"
    AT_ST((u64*)hr + (wg * 256 + tid), 0ull, __ATOMIC_RELAXED);
    __syncthreads();                    // drains all waves' stores
    if (tid == 0) AT_ST(bar + wg * 64, 1u, __ATOMIC_RELAXED);

    for (int ch = 0; ch < nChunks; ++ch) {
      const int t0 = ch * chunkT;
      const unsigned short* zxbase = zxr + (size_t)(ch % nslot) * slotE;
      if (tid == 0) {      // wait zx chunk; ONE acquire-inv per chunk (h-ring refresh too)
        while (AT_LD(gemm_done, __ATOMIC_RELAXED) < (unsigned)(ch + 1))
          __builtin_amdgcn_s_sleep(2);
        (void)AT_LD(gemm_done, __ATOMIC_ACQUIRE);
        asm volatile("" ::: "memory");
      }
      __syncthreads();
      // zx prefetch: gate-interleaved, 16 contiguous bf16 = 32 B
      union { uint4 u4[2]; unsigned short s[16]; } vv;
      {
        const unsigned short* zr = zxbase + (size_t)my_b * 4096 + wg * 64 + 16 * q;
        vv.u4[0] = *(const uint4*)zr;
        vv.u4[1] = *(const uint4*)(zr + 8);
      }
      for (int tl = 0; tl < chunkT; ++tl) {
        const int t = t0 + tl;
        const unsigned need = (unsigned)t + 1u;

        // ---- 1-hop wait: wave0 polls the 64 wg-flags (1/lane), others spin LDS ----
        if (wave == 0) {
          const unsigned* f0 = bar + lane * 64;
          for (;;) {
            int ok = (AT_LD(f0, __ATOMIC_RELAXED) >= need);
            if (__all(ok)) break;
            __builtin_amdgcn_s_sleep(1);
          }
          if (lane == 0) WG_ST(&smem.tok, need);
        } else {
          while (WG_LD(&smem.tok) < need) __builtin_amdgcn_s_sleep(1);
        }
        asm volatile("" ::: "memory");

        // ---- z_h = h @ W_slice^T: wave = b-tile, 4 n-tiles, K=1024 ----
        const unsigned short* hp =
            hr + (size_t)(t & 15) * HSLOT + (size_t)wave * 16384 + (size_t)lane * 8;
        f32x4 r0 = fz, r1 = fz, r2 = fz, r3 = fz;
        bf16x8 af[32];
#pragma unroll
        for (int j = 0; j < 32; ++j) af[j] = *(const bf16x8*)(hp + (size_t)j * 512);
#pragma unroll
        for (int j = 0; j < 32; ++j) {
          int ks = j * 32 + (lg << 3);
          bf16x8 b0 = *(const bf16x8*)&smem.u.rec.sW[l15][ks];
          bf16x8 b1 = *(const bf16x8*)&smem.u.rec.sW[16 + l15][ks];
          bf16x8 b2 = *(const bf16x8*)&smem.u.rec.sW[32 + l15][ks];
          bf16x8 b3 = *(const bf16x8*)&smem.u.rec.sW[48 + l15][ks];
          r0 = MFMA16(af[j], b0, r0);
          r1 = MFMA16(af[j], b1, r1);
          r2 = MFMA16(af[j], b2, r2);
          r3 = MFMA16(af[j], b3, r3);
        }
#pragma unroll
        for (int r = 0; r < 4; ++r) {
          int brow = wave * 16 + (lg << 2) + r;
          smem.u.rec.z[brow][l15]      = r0[r];
          smem.u.rec.z[brow][16 + l15] = r1[r];
          smem.u.rec.z[brow][32 + l15] = r2[r];
          smem.u.rec.z[brow][48 + l15] = r3[r];
        }
        __syncthreads();

        // ---- gates: thread = (b = my_b, cols c0..c0+3) ----
        int cl = 4 * q;
        float zt[4][4];
#pragma unroll
        for (int i = 0; i < 4; ++i)
#pragma unroll
          for (int g = 0; g < 4; ++g)
            zt[i][g] = smem.u.rec.z[my_b][g * 16 + cl + i] + biasv[i][g] +
                       bf2f(vv.s[4 * i + g]);
        cc0 = sigf(zt[0][1]) * cc0 + sigf(zt[0][0]) * tanh_(zt[0][2]);
        cc1 = sigf(zt[1][1]) * cc1 + sigf(zt[1][0]) * tanh_(zt[1][2]);
        cc2 = sigf(zt[2][1]) * cc2 + sigf(zt[2][0]) * tanh_(zt[2][2]);
        cc3 = sigf(zt[3][1]) * cc3 + sigf(zt[3][0]) * tanh_(zt[3][2]);
        float h0 = sigf(zt[0][3]) * tanh_(cc0);
        float h1 = sigf(zt[1][3]) * tanh_(cc1);
        float h2 = sigf(zt[2][3]) * tanh_(cc2);
        float h3 = sigf(zt[3][3]) * tanh_(cc3);

        if (t == my_tsel) {
          float* fb = finalb + (size_t)my_b * 1024 + c0;
          fb[0] = my_pad ? 0.f : h0;
          fb[1] = my_pad ? 0.f : h1;
          fb[2] = my_pad ? 0.f : h2;
          fb[3] = my_pad ? 0.f : h3;
        }
        u64 hp64 = (u64)f2bf(h0) | ((u64)f2bf(h1) << 16) |
                   ((u64)f2bf(h2) << 32) | ((u64)f2bf(h3) << 48);
        AT_ST((u64*)(hr + (size_t)((t + 1) & 15) * HSLOT + hwe), hp64,
              __ATOMIC_RELAXED);

        if (tl + 1 < chunkT) {   // prefetch next step's zx
          const unsigned short* zn =
              zxbase + (size_t)((tl + 1) * 64 + my_b) * 4096 + wg * 64 + 16 * q;
          vv.u4[0] = *(const uint4*)zn;
          vv.u4[1] = *(const uint4*)(zn + 8);
        }
        __syncthreads();         // all waves' h stores drained
        if (tid == 0) AT_ST(bar + wg * 64, need + 1u, __ATOMIC_RELAXED);
      }
      if (wg == 0 && tid == 0) AT_ST(rec_done, (unsigned)(ch + 1), __ATOMIC_RELAXED);
    }
  } else {
    // ============ GEMM ROLE (front-loads nslot chunks, then trickles; exits) ========
    const int gw = wg - 64;
    unsigned gt = 0;
    for (int ch = 0; ch < nChunks; ++ch) {
      if (tid == 0 && ch >= nslot) {
        while (AT_LD(rec_done, __ATOMIC_RELAXED) < (unsigned)(ch - nslot + 1))
          __builtin_amdgcn_s_sleep(8);
        asm volatile("" ::: "memory");
      }
      __syncthreads();
      const int t0 = ch * chunkT;
      unsigned short* zx = zxr + (size_t)(ch % nslot) * slotE;
      const int pmN = chunkT >> 1;
      const int npatch = pmN * 16;
      for (int p = gw; p < npatch; p += 128) {
        const int pm = p % pmN;
        const int n0 = (p / pmN) * 256;
        f32x4 acc[8][4];
#pragma unroll
        for (int mt = 0; mt < 8; ++mt)
#pragma unroll
          for (int nt = 0; nt < 4; ++nt) acc[mt][nt] = fz;
        for (int kc = 0; kc < 512; kc += 64) {
          __syncthreads();
          {
            int r = tid >> 1, half = (tid & 1) << 5;
            int tl = pm * 2 + (r >> 6), b = r & 63;
            int erow = x[b * 512 + t0 + tl];
            if (wembb) {
              const unsigned short* srcp = wembb + (size_t)erow * 512 + kc + half;
#pragma unroll
              for (int j = 0; j < 32; j += 8)
                *(uint4*)&smem.u.g.A[r][half + j] = *(const uint4*)(srcp + j);
            } else {
              const float* srcp = Wemb + (size_t)erow * 512 + kc + half;
#pragma unroll
              for (int j = 0; j < 32; j += 4) {
                float4 v = *(const float4*)(srcp + j);
                uint2 pk;
                pk.x = (unsigned)f2bf(v.x) | ((unsigned)f2bf(v.y) << 16);
                pk.y = (unsigned)f2bf(v.z) | ((unsigned)f2bf(v.w) << 16);
                *(uint2*)&smem.u.g.A[r][half + j] = pk;
              }
            }
          }
          {
            int zcx = n0 + tid;
            int wrow = (zcx & 3) * 1024 + (zcx >> 2);
            const unsigned short* srcp = Wihb + (size_t)wrow * 512 + kc;
#pragma unroll
            for (int j = 0; j < 64; j += 8)
              *(uint4*)&smem.u.g.Bt[tid][j] = *(const uint4*)(srcp + j);
          }
          __syncthreads();
#pragma unroll
          for (int ks = 0; ks < 64; ks += 32) {
            bf16x8 af[8];
#pragma unroll
            for (int mt = 0; mt < 8; ++mt)
              af[mt] = *(const bf16x8*)&smem.u.g.A[mt * 16 + l15][ks + (lg << 3)];
#pragma unroll
            for (int nt = 0; nt < 4; ++nt) {
              bf16x8 bfr =
                  *(const bf16x8*)&smem.u.g.Bt[(wave * 4 + nt) * 16 + l15][ks + (lg << 3)];
#pragma unroll
              for (int mt = 0; mt < 8; ++mt)
                acc[mt][nt] = MFMA16(af[mt], bfr, acc[mt][nt]);
            }
          }
        }
#pragma unroll
        for (int h = 0; h < 2; ++h) {
          __syncthreads();
          if ((wave >> 1) == h) {
#pragma unroll
            for (int mt = 0; mt < 8; ++mt)
#pragma unroll
              for (int nt = 0; nt < 4; ++nt)
#pragma unroll
                for (int r = 0; r < 4; ++r)
                  smem.u.zst.zs[mt * 16 + (lg << 2) + r][(wave & 1) * 64 + nt * 16 + l15] =
                      f2bf(acc[mt][nt][r]);
          }
          __syncthreads();
          int m = tid >> 1, qq = (tid & 1) << 6;
          int tl2 = pm * 2 + (m >> 6), bb = m & 63;
          unsigned short* dst = zx + ((size_t)(tl2 * 64 + bb)) * 4096 + n0 + h * 128 + qq;
#pragma unroll
          for (int j = 0; j < 64; j += 8)
            *(uint4*)(dst + j) = *(const uint4*)&smem.u.zst.zs[m][qq + j];
        }
      }
      gbar_gemm(bar, ++gt);
      if (wg == 64 && tid == 0) AT_ST(gemm_done, gt, __ATOMIC_RELAXED);
    }
  }
}

extern "C" void kernel_launch(void* const* d_in, const int* in_sizes, int n_in,
                              void* d_out, int out_size, void* d_ws, size_t ws_size,
                              hipStream_t stream) {
  (void)in_sizes; (void)n_in; (void)out_size;
  const int*   x    = (const int*)  d_in[0];
  const float* Wemb = (const float*)d_in[1];
  const float* Wih  = (const float*)d_in[2];
  const float* Whh  = (const float*)d_in[3];
  const float* bih  = (const float*)d_in[4];
  const float* bhh  = (const float*)d_in[5];
  const float* Wout = (const float*)d_in[6];
  const float* bout = (const float*)d_in[7];
  float* out = (float*)d_out;
  char* ws = (char*)d_ws;

  constexpr size_t OFF_WIH = 0;
  constexpr size_t OFF_WHH = OFF_WIH + (size_t)4096 * 512 * 2;    //  4 MB
  constexpr size_t OFF_HR  = OFF_WHH + (size_t)4096 * 1024 * 2;   // +8 MB
  constexpr size_t OFF_FIN = OFF_HR + (size_t)16 * HSLOT * 2;     // +2.06 MB
  constexpr size_t OFF_TS  = OFF_FIN + (size_t)64 * 1024 * 4;     // +256 KB
  constexpr size_t OFF_PS  = OFF_TS + 4096;
  constexpr size_t OFF_BAR = OFF_PS + 4096;
  constexpr size_t OFF_WEB = OFF_BAR + 40960;                     // 40 KB barrier zone
  constexpr size_t WEB_SZ  = (size_t)32000 * 512 * 2;             // 32 MB
  constexpr size_t SLOT_SZ = (size_t)16 * 64 * 4096 * 2;          // 8 MB per chunk slot

  int chunkT = 16;
  bool wbf = true;
  int nslot = 2;
  if (OFF_WEB + WEB_SZ + 2 * SLOT_SZ <= ws_size) {
    nslot = (int)((ws_size - OFF_WEB - WEB_SZ) / SLOT_SZ);
    if (nslot > 32) nslot = 32;
  } else if (OFF_WEB + 2 * SLOT_SZ <= ws_size) {
    wbf = false;
    nslot = (int)((ws_size - OFF_WEB) / SLOT_SZ);
    if (nslot > 32) nslot = 32;
  } else {
    wbf = false;
    while (chunkT > 2 &&
           OFF_WEB + (size_t)2 * chunkT * 64 * 4096 * 2 > ws_size)
      chunkT >>= 1;
  }
  const size_t OFF_ZX = OFF_WEB + (wbf ? WEB_SZ : 0);

  unsigned short* wihb  = (unsigned short*)(ws + OFF_WIH);
  unsigned short* whhb  = (unsigned short*)(ws + OFF_WHH);
  unsigned short* hr    = (unsigned short*)(ws + OFF_HR);
  float* finalb         = (float*)(ws + OFF_FIN);
  int* tsel             = (int*)(ws + OFF_TS);
  int* padsel           = (int*)(ws + OFF_PS);
  unsigned* bar         = (unsigned*)(ws + OFF_BAR);
  unsigned short* wembb = wbf ? (unsigned short*)(ws + OFF_WEB) : (unsigned short*)nullptr;
  unsigned short* zxr   = (unsigned short*)(ws + OFF_ZX);

  hipMemsetAsync(ws + OFF_BAR, 0, 40960, stream);
  k_conv<<<2048, 256, 0, stream>>>(Wih, Whh, Wemb, wihb, whhb, wembb);
  k_tsel<<<1, 512, 0, stream>>>(x, tsel, padsel);
  k_main<<<192, 256, 0, stream>>>(x, Wemb, bih, bhh, wihb, whhb, wembb, hr, finalb,
                                  tsel, padsel, zxr, bar, chunkT, nslot);
  k_logits<<<1, 256, 0, stream>>>(finalb, Wout, bout, out);
}

// Round 13
// 4972.574 us; speedup vs baseline: 3.0871x; 3.0871x over previous
//
#include <hip/hip_runtime.h>

typedef short bf16x8 __attribute__((ext_vector_type(8)));
typedef float f32x4  __attribute__((ext_vector_type(4)));
typedef unsigned long long u64;

#define MFMA16(a, b, c) __builtin_amdgcn_mfma_f32_16x16x32_bf16((a), (b), (c), 0, 0, 0)
#define AT_LD(p, o)    __hip_atomic_load((p), (o), __HIP_MEMORY_SCOPE_AGENT)
#define AT_ST(p, v, o) __hip_atomic_store((p), (v), (o), __HIP_MEMORY_SCOPE_AGENT)
#define AT_ADD(p, v, o) __hip_atomic_fetch_add((p), (v), (o), __HIP_MEMORY_SCOPE_AGENT)
#define WG_LD(p) __hip_atomic_load((p), __ATOMIC_RELAXED, __HIP_MEMORY_SCOPE_WORKGROUP)
#define WG_ST(p, v) __hip_atomic_store((p), (v), __ATOMIC_RELAXED, __HIP_MEMORY_SCOPE_WORKGROUP)

#define HSLOT 67584      // h ring slot stride in bf16 elems (128KB + 4KB pad)

// barrier zone (words): flags[wg]=wg*64 (0..4032, 64 wgs), gemm tree 8256(cnt)/8320(gen),
// gemm_done=8384, rec_done=8448
__device__ __forceinline__ unsigned short f2bf(float f) {
  union { float f; unsigned u; } v; v.f = f;
  unsigned u = v.u;
  u += 0x7fffu + ((u >> 16) & 1u);
  return (unsigned short)(u >> 16);
}
__device__ __forceinline__ float bf2f(unsigned short h) {
  union { unsigned u; float f; } v; v.u = ((unsigned)h) << 16;
  return v.f;
}
__device__ __forceinline__ float sigf(float x) { return 1.f / (1.f + __expf(-x)); }
__device__ __forceinline__ float tanh_(float x) {
  x = fminf(15.f, fmaxf(-15.f, x));
  float e = __expf(2.f * x);
  return (e - 1.f) / (e + 1.f);
}

// ---- per-chunk release barrier for the 128 GEMM wgs ----
__device__ __forceinline__ void gbar_gemm(unsigned* bar, unsigned target) {
  __syncthreads();
  if (threadIdx.x == 0) {
    unsigned arr = AT_ADD(bar + 8256, 1u, __ATOMIC_RELEASE);  // vmcnt drain + L2 wb
    if (arr == target * 128u - 1u) AT_ST(bar + 8320, target, __ATOMIC_RELEASE);
    while (AT_LD(bar + 8320, __ATOMIC_RELAXED) < target) __builtin_amdgcn_s_sleep(4);
    asm volatile("" ::: "memory");
  }
  __syncthreads();
}

// ---------------- weight conversion fp32 -> bf16 ----------------
__global__ void k_conv(const float* __restrict__ wih, const float* __restrict__ whh,
                       const float* __restrict__ wemb,
                       unsigned short* __restrict__ oih, unsigned short* __restrict__ ohh,
                       unsigned short* __restrict__ oemb) {
  const size_t NIH = (size_t)4096 * 512, NHH = (size_t)4096 * 1024;
  const size_t NE = (size_t)32000 * 512;
  size_t i0 = ((size_t)blockIdx.x * blockDim.x + threadIdx.x) * 4;
  size_t gs = (size_t)gridDim.x * blockDim.x * 4;
  for (size_t j = i0; j < NIH; j += gs) {
    float4 v = *(const float4*)(wih + j);
    uint2 pk;
    pk.x = (unsigned)f2bf(v.x) | ((unsigned)f2bf(v.y) << 16);
    pk.y = (unsigned)f2bf(v.z) | ((unsigned)f2bf(v.w) << 16);
    *(uint2*)(oih + j) = pk;
  }
  for (size_t j = i0; j < NHH; j += gs) {
    float4 v = *(const float4*)(whh + j);
    uint2 pk;
    pk.x = (unsigned)f2bf(v.x) | ((unsigned)f2bf(v.y) << 16);
    pk.y = (unsigned)f2bf(v.z) | ((unsigned)f2bf(v.w) << 16);
    *(uint2*)(ohh + j) = pk;
  }
  if (oemb)
    for (size_t j = i0; j < NE; j += gs) {
      float4 v = *(const float4*)(wemb + j);
      uint2 pk;
      pk.x = (unsigned)f2bf(v.x) | ((unsigned)f2bf(v.y) << 16);
      pk.y = (unsigned)f2bf(v.z) | ((unsigned)f2bf(v.w) << 16);
      *(uint2*)(oemb + j) = pk;
    }
}

// ---------------- lengths / selection index ----------------
__global__ void k_tsel(const int* __restrict__ x, int* __restrict__ tsel,
                       int* __restrict__ padsel) {
  int b = threadIdx.x >> 3, j = threadIdx.x & 7;
  int c = 0;
  for (int t = j * 64; t < j * 64 + 64; ++t) c += (x[b * 512 + t] != 1) ? 1 : 0;
  c += __shfl_xor(c, 1);
  c += __shfl_xor(c, 2);
  c += __shfl_xor(c, 4);
  if (j == 0) {
    int ts = (c - 1) & 511;                        // len==0 wraps to T-1
    tsel[b] = ts;
    padsel[b] = (x[b * 512 + ts] == 1) ? 1 : 0;
  }
}

// ---------------- final logits: [64,1024] @ [8,1024]^T + b ----------------
__global__ void k_logits(const float* __restrict__ finalb, const float* __restrict__ Wout,
                         const float* __restrict__ bout, float* __restrict__ out) {
  int tid = threadIdx.x;
  for (int e = tid; e < 512; e += 256) {
    int b = e >> 3, o = e & 7;
    const float* f = finalb + (size_t)b * 1024;
    const float* w = Wout + (size_t)o * 1024;
    float s = 0.f;
    for (int k = 0; k < 1024; ++k) s += f[k] * w[k];
    out[e] = s + bout[o];
  }
}

// ---------------- main kernel: 192 wgs = 64 rec (16 cols each) + 128 GEMM ----------------
struct SmemT {
  unsigned tok;                                      // rec: barrier token (LDS)
  union {
    struct {
      unsigned short sW[64][1032];                   // W_hh slice, PADDED row stride
      float z[64][68];                               // z exchange: [b][zrow 0..63]
    } rec;
    struct { unsigned short A[128][72]; unsigned short Bt[256][72]; } g;
    struct { unsigned short zs[128][136]; } zst;
  } u;
};

__global__ __launch_bounds__(256, 1) void k_main(
    const int* __restrict__ x, const float* __restrict__ Wemb,
    const float* __restrict__ bih, const float* __restrict__ bhh,
    const unsigned short* __restrict__ Wihb, const unsigned short* __restrict__ Whhb,
    const unsigned short* __restrict__ wembb,
    unsigned short* __restrict__ hr, float* __restrict__ finalb,
    const int* __restrict__ tsel, const int* __restrict__ padsel,
    unsigned short* __restrict__ zxr, unsigned* __restrict__ bar, int chunkT,
    int nslot) {
  __shared__ SmemT smem;
  const int wg = blockIdx.x, tid = threadIdx.x;
  const int wave = tid >> 6, lane = tid & 63;
  const int l15 = lane & 15, lg = lane >> 4;
  unsigned* gemm_done = bar + 8384;
  unsigned* rec_done  = bar + 8448;
  const f32x4 fz = {0.f, 0.f, 0.f, 0.f};
  const int nChunks = 512 / chunkT;
  const size_t slotE = (size_t)chunkT * 64 * 4096;

  if (wg < 64) {
    // ================= RECURRENT ROLE: 16 h-cols, 64 z-rows =================
    if (tid == 0) smem.tok = 0;
    // sW fill: z-row r -> global W row (r>>4)*1024 + wg*16 + (r&15)
    for (int e = tid; e < 64 * 128; e += 256) {
      int r = e >> 7, kq = (e & 127) << 3;
      int grow = (r >> 4) * 1024 + wg * 16 + (r & 15);
      *(uint4*)&smem.u.rec.sW[r][kq] = *(const uint4*)(Whhb + (size_t)grow * 1024 + kq);
    }
    const int q = tid & 3;
    const int my_b = tid >> 2;
    const int c0 = wg * 16 + 4 * q;                  // first of this thread's 4 cols
    float biasv[4][4];                               // [i][g]
#pragma unroll
    for (int i = 0; i < 4; ++i)
#pragma unroll
      for (int g = 0; g < 4; ++g)
        biasv[i][g] = bih[g * 1024 + c0 + i] + bhh[g * 1024 + c0 + i];
    const int my_tsel = tsel[my_b];
    const int my_pad = padsel[my_b];
    // frag-order store: k = c0 + i (i=0..3 contiguous within k&7): one u64 store
    const size_t hwe = (size_t)(my_b >> 4) * 16384 + (size_t)(wg >> 1) * 512 +
                       (size_t)((wg * 2 + (q >> 1)) & 3) * 128 +
                       (size_t)(my_b & 15) * 8 + (size_t)(q & 1) * 4;
    float cc0 = 0.f, cc1 = 0.f, cc2 = 0.f, cc3 = 0.f;

    // zero h slot 0 (64 wg x 256 thr x 8B = 128KB); flag=1 means "h_0 visible"
    AT_ST((u64*)hr + (wg * 256 + tid), 0ull, __ATOMIC_RELAXED);
    __syncthreads();                    // drains all waves' stores
    if (tid == 0) AT_ST(bar + wg * 64, 1u, __ATOMIC_RELAXED);

    for (int ch = 0; ch < nChunks; ++ch) {
      const int t0 = ch * chunkT;
      const unsigned short* zxbase = zxr + (size_t)(ch % nslot) * slotE;
      if (tid == 0) {      // wait zx chunk; ONE acquire-inv per chunk (h-ring refresh too)
        while (AT_LD(gemm_done, __ATOMIC_RELAXED) < (unsigned)(ch + 1))
          __builtin_amdgcn_s_sleep(2);
        (void)AT_LD(gemm_done, __ATOMIC_ACQUIRE);
        asm volatile("" ::: "memory");
      }
      __syncthreads();
      // zx prefetch: gate-interleaved, 16 contiguous bf16 = 32 B
      union { uint4 u4[2]; unsigned short s[16]; } vv;
      {
        const unsigned short* zr = zxbase + (size_t)my_b * 4096 + wg * 64 + 16 * q;
        vv.u4[0] = *(const uint4*)zr;
        vv.u4[1] = *(const uint4*)(zr + 8);
      }
      for (int tl = 0; tl < chunkT; ++tl) {
        const int t = t0 + tl;
        const unsigned need = (unsigned)t + 1u;

        // ---- 1-hop wait: wave0 polls the 64 wg-flags (1/lane), others spin LDS ----
        if (wave == 0) {
          const unsigned* f0 = bar + lane * 64;
          for (;;) {
            int ok = (AT_LD(f0, __ATOMIC_RELAXED) >= need);
            if (__all(ok)) break;
            __builtin_amdgcn_s_sleep(1);
          }
          if (lane == 0) WG_ST(&smem.tok, need);
        } else {
          while (WG_LD(&smem.tok) < need) __builtin_amdgcn_s_sleep(1);
        }
        asm volatile("" ::: "memory");

        // ---- z_h = h @ W_slice^T: wave = b-tile, 4 n-tiles, K=1024 ----
        const unsigned short* hp =
            hr + (size_t)(t & 15) * HSLOT + (size_t)wave * 16384 + (size_t)lane * 8;
        f32x4 r0 = fz, r1 = fz, r2 = fz, r3 = fz;
        bf16x8 af[32];
#pragma unroll
        for (int j = 0; j < 32; ++j) af[j] = *(const bf16x8*)(hp + (size_t)j * 512);
#pragma unroll
        for (int j = 0; j < 32; ++j) {
          int ks = j * 32 + (lg << 3);
          bf16x8 b0 = *(const bf16x8*)&smem.u.rec.sW[l15][ks];
          bf16x8 b1 = *(const bf16x8*)&smem.u.rec.sW[16 + l15][ks];
          bf16x8 b2 = *(const bf16x8*)&smem.u.rec.sW[32 + l15][ks];
          bf16x8 b3 = *(const bf16x8*)&smem.u.rec.sW[48 + l15][ks];
          r0 = MFMA16(af[j], b0, r0);
          r1 = MFMA16(af[j], b1, r1);
          r2 = MFMA16(af[j], b2, r2);
          r3 = MFMA16(af[j], b3, r3);
        }
#pragma unroll
        for (int r = 0; r < 4; ++r) {
          int brow = wave * 16 + (lg << 2) + r;
          smem.u.rec.z[brow][l15]      = r0[r];
          smem.u.rec.z[brow][16 + l15] = r1[r];
          smem.u.rec.z[brow][32 + l15] = r2[r];
          smem.u.rec.z[brow][48 + l15] = r3[r];
        }
        __syncthreads();

        // ---- gates: thread = (b = my_b, cols c0..c0+3) ----
        int cl = 4 * q;
        float zt[4][4];
#pragma unroll
        for (int i = 0; i < 4; ++i)
#pragma unroll
          for (int g = 0; g < 4; ++g)
            zt[i][g] = smem.u.rec.z[my_b][g * 16 + cl + i] + biasv[i][g] +
                       bf2f(vv.s[4 * i + g]);
        cc0 = sigf(zt[0][1]) * cc0 + sigf(zt[0][0]) * tanh_(zt[0][2]);
        cc1 = sigf(zt[1][1]) * cc1 + sigf(zt[1][0]) * tanh_(zt[1][2]);
        cc2 = sigf(zt[2][1]) * cc2 + sigf(zt[2][0]) * tanh_(zt[2][2]);
        cc3 = sigf(zt[3][1]) * cc3 + sigf(zt[3][0]) * tanh_(zt[3][2]);
        float h0 = sigf(zt[0][3]) * tanh_(cc0);
        float h1 = sigf(zt[1][3]) * tanh_(cc1);
        float h2 = sigf(zt[2][3]) * tanh_(cc2);
        float h3 = sigf(zt[3][3]) * tanh_(cc3);

        if (t == my_tsel) {
          float* fb = finalb + (size_t)my_b * 1024 + c0;
          fb[0] = my_pad ? 0.f : h0;
          fb[1] = my_pad ? 0.f : h1;
          fb[2] = my_pad ? 0.f : h2;
          fb[3] = my_pad ? 0.f : h3;
        }
        u64 hp64 = (u64)f2bf(h0) | ((u64)f2bf(h1) << 16) |
                   ((u64)f2bf(h2) << 32) | ((u64)f2bf(h3) << 48);
        AT_ST((u64*)(hr + (size_t)((t + 1) & 15) * HSLOT + hwe), hp64,
              __ATOMIC_RELAXED);

        if (tl + 1 < chunkT) {   // prefetch next step's zx
          const unsigned short* zn =
              zxbase + (size_t)((tl + 1) * 64 + my_b) * 4096 + wg * 64 + 16 * q;
          vv.u4[0] = *(const uint4*)zn;
          vv.u4[1] = *(const uint4*)(zn + 8);
        }
        __syncthreads();         // all waves' h stores drained
        if (tid == 0) AT_ST(bar + wg * 64, need + 1u, __ATOMIC_RELAXED);
      }
      if (wg == 0 && tid == 0) AT_ST(rec_done, (unsigned)(ch + 1), __ATOMIC_RELAXED);
    }
  } else {
    // ============ GEMM ROLE (front-loads nslot chunks, then trickles; exits) ========
    const int gw = wg - 64;
    unsigned gt = 0;
    for (int ch = 0; ch < nChunks; ++ch) {
      if (tid == 0 && ch >= nslot) {
        while (AT_LD(rec_done, __ATOMIC_RELAXED) < (unsigned)(ch - nslot + 1))
          __builtin_amdgcn_s_sleep(8);
        asm volatile("" ::: "memory");
      }
      __syncthreads();
      const int t0 = ch * chunkT;
      unsigned short* zx = zxr + (size_t)(ch % nslot) * slotE;
      const int pmN = chunkT >> 1;
      const int npatch = pmN * 16;
      for (int p = gw; p < npatch; p += 128) {
        const int pm = p % pmN;
        const int n0 = (p / pmN) * 256;
        f32x4 acc[8][4];
#pragma unroll
        for (int mt = 0; mt < 8; ++mt)
#pragma unroll
          for (int nt = 0; nt < 4; ++nt) acc[mt][nt] = fz;
        for (int kc = 0; kc < 512; kc += 64) {
          __syncthreads();
          {
            int r = tid >> 1, half = (tid & 1) << 5;
            int tl = pm * 2 + (r >> 6), b = r & 63;
            int erow = x[b * 512 + t0 + tl];
            if (wembb) {
              const unsigned short* srcp = wembb + (size_t)erow * 512 + kc + half;
#pragma unroll
              for (int j = 0; j < 32; j += 8)
                *(uint4*)&smem.u.g.A[r][half + j] = *(const uint4*)(srcp + j);
            } else {
              const float* srcp = Wemb + (size_t)erow * 512 + kc + half;
#pragma unroll
              for (int j = 0; j < 32; j += 4) {
                float4 v = *(const float4*)(srcp + j);
                uint2 pk;
                pk.x = (unsigned)f2bf(v.x) | ((unsigned)f2bf(v.y) << 16);
                pk.y = (unsigned)f2bf(v.z) | ((unsigned)f2bf(v.w) << 16);
                *(uint2*)&smem.u.g.A[r][half + j] = pk;
              }
            }
          }
          {
            int zcx = n0 + tid;
            int wrow = (zcx & 3) * 1024 + (zcx >> 2);
            const unsigned short* srcp = Wihb + (size_t)wrow * 512 + kc;
#pragma unroll
            for (int j = 0; j < 64; j += 8)
              *(uint4*)&smem.u.g.Bt[tid][j] = *(const uint4*)(srcp + j);
          }
          __syncthreads();
#pragma unroll
          for (int ks = 0; ks < 64; ks += 32) {
            bf16x8 af[8];
#pragma unroll
            for (int mt = 0; mt < 8; ++mt)
              af[mt] = *(const bf16x8*)&smem.u.g.A[mt * 16 + l15][ks + (lg << 3)];
#pragma unroll
            for (int nt = 0; nt < 4; ++nt) {
              bf16x8 bfr =
                  *(const bf16x8*)&smem.u.g.Bt[(wave * 4 + nt) * 16 + l15][ks + (lg << 3)];
#pragma unroll
              for (int mt = 0; mt < 8; ++mt)
                acc[mt][nt] = MFMA16(af[mt], bfr, acc[mt][nt]);
            }
          }
        }
#pragma unroll
        for (int h = 0; h < 2; ++h) {
          __syncthreads();
          if ((wave >> 1) == h) {
#pragma unroll
            for (int mt = 0; mt < 8; ++mt)
#pragma unroll
              for (int nt = 0; nt < 4; ++nt)
#pragma unroll
                for (int r = 0; r < 4; ++r)
                  smem.u.zst.zs[mt * 16 + (lg << 2) + r][(wave & 1) * 64 + nt * 16 + l15] =
                      f2bf(acc[mt][nt][r]);
          }
          __syncthreads();
          int m = tid >> 1, qq = (tid & 1) << 6;
          int tl2 = pm * 2 + (m >> 6), bb = m & 63;
          unsigned short* dst = zx + ((size_t)(tl2 * 64 + bb)) * 4096 + n0 + h * 128 + qq;
#pragma unroll
          for (int j = 0; j < 64; j += 8)
            *(uint4*)(dst + j) = *(const uint4*)&smem.u.zst.zs[m][qq + j];
        }
      }
      gbar_gemm(bar, ++gt);
      if (wg == 64 && tid == 0) AT_ST(gemm_done, gt, __ATOMIC_RELAXED);
    }
  }
}

extern "C" void kernel_launch(void* const* d_in, const int* in_sizes, int n_in,
                              void* d_out, int out_size, void* d_ws, size_t ws_size,
                              hipStream_t stream) {
  (void)in_sizes; (void)n_in; (void)out_size;
  const int*   x    = (const int*)  d_in[0];
  const float* Wemb = (const float*)d_in[1];
  const float* Wih  = (const float*)d_in[2];
  const float* Whh  = (const float*)d_in[3];
  const float* bih  = (const float*)d_in[4];
  const float* bhh  = (const float*)d_in[5];
  const float* Wout = (const float*)d_in[6];
  const float* bout = (const float*)d_in[7];
  float* out = (float*)d_out;
  char* ws = (char*)d_ws;

  constexpr size_t OFF_WIH = 0;
  constexpr size_t OFF_WHH = OFF_WIH + (size_t)4096 * 512 * 2;    //  4 MB
  constexpr size_t OFF_HR  = OFF_WHH + (size_t)4096 * 1024 * 2;   // +8 MB
  constexpr size_t OFF_FIN = OFF_HR + (size_t)16 * HSLOT * 2;     // +2.06 MB
  constexpr size_t OFF_TS  = OFF_FIN + (size_t)64 * 1024 * 4;     // +256 KB
  constexpr size_t OFF_PS  = OFF_TS + 4096;
  constexpr size_t OFF_BAR = OFF_PS + 4096;
  constexpr size_t OFF_WEB = OFF_BAR + 40960;                     // 40 KB barrier zone
  constexpr size_t WEB_SZ  = (size_t)32000 * 512 * 2;             // 32 MB
  constexpr size_t SLOT_SZ = (size_t)16 * 64 * 4096 * 2;          // 8 MB per chunk slot

  int chunkT = 16;
  bool wbf = true;
  int nslot = 2;
  if (OFF_WEB + WEB_SZ + 2 * SLOT_SZ <= ws_size) {
    nslot = (int)((ws_size - OFF_WEB - WEB_SZ) / SLOT_SZ);
    if (nslot > 32) nslot = 32;
  } else if (OFF_WEB + 2 * SLOT_SZ <= ws_size) {
    wbf = false;
    nslot = (int)((ws_size - OFF_WEB) / SLOT_SZ);
    if (nslot > 32) nslot = 32;
  } else {
    wbf = false;
    while (chunkT > 2 &&
           OFF_WEB + (size_t)2 * chunkT * 64 * 4096 * 2 > ws_size)
      chunkT >>= 1;
  }
  const size_t OFF_ZX = OFF_WEB + (wbf ? WEB_SZ : 0);

  unsigned short* wihb  = (unsigned short*)(ws + OFF_WIH);
  unsigned short* whhb  = (unsigned short*)(ws + OFF_WHH);
  unsigned short* hr    = (unsigned short*)(ws + OFF_HR);
  float* finalb         = (float*)(ws + OFF_FIN);
  int* tsel             = (int*)(ws + OFF_TS);
  int* padsel           = (int*)(ws + OFF_PS);
  unsigned* bar         = (unsigned*)(ws + OFF_BAR);
  unsigned short* wembb = wbf ? (unsigned short*)(ws + OFF_WEB) : (unsigned short*)nullptr;
  unsigned short* zxr   = (unsigned short*)(ws + OFF_ZX);

  hipMemsetAsync(ws + OFF_BAR, 0, 40960, stream);
  k_conv<<<2048, 256, 0, stream>>>(Wih, Whh, Wemb, wihb, whhb, wembb);
  k_tsel<<<1, 512, 0, stream>>>(x, tsel, padsel);
  k_main<<<192, 256, 0, stream>>>(x, Wemb, bih, bhh, wihb, whhb, wembb, hr, finalb,
                                  tsel, padsel, zxr, bar, chunkT, nslot);
  k_logits<<<1, 256, 0, stream>>>(finalb, Wout, bout, out);
}

// Round 14
// 3156.265 us; speedup vs baseline: 4.8636x; 1.5755x over previous
//
#include <hip/hip_runtime.h>

typedef short bf16x8 __attribute__((ext_vector_type(8)));
typedef float f32x4  __attribute__((ext_vector_type(4)));
typedef unsigned long long u64;

#define MFMA16(a, b, c) __builtin_amdgcn_mfma_f32_16x16x32_bf16((a), (b), (c), 0, 0, 0)
#define AT_LD(p, o)    __hip_atomic_load((p), (o), __HIP_MEMORY_SCOPE_AGENT)
#define AT_ST(p, v, o) __hip_atomic_store((p), (v), (o), __HIP_MEMORY_SCOPE_AGENT)
#define AT_ADD(p, v, o) __hip_atomic_fetch_add((p), (v), (o), __HIP_MEMORY_SCOPE_AGENT)
#define WG_LD(p) __hip_atomic_load((p), __ATOMIC_RELAXED, __HIP_MEMORY_SCOPE_WORKGROUP)
#define WG_ST(p, v) __hip_atomic_store((p), (v), __ATOMIC_RELAXED, __HIP_MEMORY_SCOPE_WORKGROUP)

#define HSLOT 67584      // h ring slot stride in bf16 elems (128KB + 4KB pad)

// barrier zone (words): flags[wg]=wg*64 (0..8128), gemm tree 8256(cnt)/8320(gen),
// gemm_done=8384, rec_done=8448
__device__ __forceinline__ unsigned short f2bf(float f) {
  union { float f; unsigned u; } v; v.f = f;
  unsigned u = v.u;
  u += 0x7fffu + ((u >> 16) & 1u);
  return (unsigned short)(u >> 16);
}
__device__ __forceinline__ float bf2f(unsigned short h) {
  union { unsigned u; float f; } v; v.u = ((unsigned)h) << 16;
  return v.f;
}
__device__ __forceinline__ float sigf(float x) { return 1.f / (1.f + __expf(-x)); }
__device__ __forceinline__ float tanh_(float x) {
  x = fminf(15.f, fmaxf(-15.f, x));
  float e = __expf(2.f * x);
  return (e - 1.f) / (e + 1.f);
}

// ---- per-chunk release barrier for the 128 GEMM wgs ----
__device__ __forceinline__ void gbar_gemm(unsigned* bar, unsigned target) {
  __syncthreads();
  if (threadIdx.x == 0) {
    unsigned arr = AT_ADD(bar + 8256, 1u, __ATOMIC_RELEASE);  // vmcnt drain + L2 wb
    if (arr == target * 128u - 1u) AT_ST(bar + 8320, target, __ATOMIC_RELEASE);
    while (AT_LD(bar + 8320, __ATOMIC_RELAXED) < target) __builtin_amdgcn_s_sleep(4);
    asm volatile("" ::: "memory");
  }
  __syncthreads();
}

// ---------------- weight conversion fp32 -> bf16 ----------------
__global__ void k_conv(const float* __restrict__ wih, const float* __restrict__ whh,
                       const float* __restrict__ wemb,
                       unsigned short* __restrict__ oih, unsigned short* __restrict__ ohh,
                       unsigned short* __restrict__ oemb) {
  const size_t NIH = (size_t)4096 * 512, NHH = (size_t)4096 * 1024;
  const size_t NE = (size_t)32000 * 512;
  size_t i0 = ((size_t)blockIdx.x * blockDim.x + threadIdx.x) * 4;
  size_t gs = (size_t)gridDim.x * blockDim.x * 4;
  for (size_t j = i0; j < NIH; j += gs) {
    float4 v = *(const float4*)(wih + j);
    uint2 pk;
    pk.x = (unsigned)f2bf(v.x) | ((unsigned)f2bf(v.y) << 16);
    pk.y = (unsigned)f2bf(v.z) | ((unsigned)f2bf(v.w) << 16);
    *(uint2*)(oih + j) = pk;
  }
  for (size_t j = i0; j < NHH; j += gs) {
    float4 v = *(const float4*)(whh + j);
    uint2 pk;
    pk.x = (unsigned)f2bf(v.x) | ((unsigned)f2bf(v.y) << 16);
    pk.y = (unsigned)f2bf(v.z) | ((unsigned)f2bf(v.w) << 16);
    *(uint2*)(ohh + j) = pk;
  }
  if (oemb)
    for (size_t j = i0; j < NE; j += gs) {
      float4 v = *(const float4*)(wemb + j);
      uint2 pk;
      pk.x = (unsigned)f2bf(v.x) | ((unsigned)f2bf(v.y) << 16);
      pk.y = (unsigned)f2bf(v.z) | ((unsigned)f2bf(v.w) << 16);
      *(uint2*)(oemb + j) = pk;
    }
}

// ---------------- lengths / selection index ----------------
__global__ void k_tsel(const int* __restrict__ x, int* __restrict__ tsel,
                       int* __restrict__ padsel) {
  int b = threadIdx.x >> 3, j = threadIdx.x & 7;
  int c = 0;
  for (int t = j * 64; t < j * 64 + 64; ++t) c += (x[b * 512 + t] != 1) ? 1 : 0;
  c += __shfl_xor(c, 1);
  c += __shfl_xor(c, 2);
  c += __shfl_xor(c, 4);
  if (j == 0) {
    int ts = (c - 1) & 511;                        // len==0 wraps to T-1
    tsel[b] = ts;
    padsel[b] = (x[b * 512 + ts] == 1) ? 1 : 0;
  }
}

// ---------------- final logits: [64,1024] @ [8,1024]^T + b ----------------
__global__ void k_logits(const float* __restrict__ finalb, const float* __restrict__ Wout,
                         const float* __restrict__ bout, float* __restrict__ out) {
  int tid = threadIdx.x;
  for (int e = tid; e < 512; e += 256) {
    int b = e >> 3, o = e & 7;
    const float* f = finalb + (size_t)b * 1024;
    const float* w = Wout + (size_t)o * 1024;
    float s = 0.f;
    for (int k = 0; k < 1024; ++k) s += f[k] * w[k];
    out[e] = s + bout[o];
  }
}

// ---------------- main kernel: 256 wgs = 128 rec + 128 GEMM ----------------
// Rec: swapped-operand MFMA (A=W gate-interleaved, B=h) => gates are lane-local,
// no LDS z-exchange. h ring layout: [slot][btile][kgrp][b&15][k&7].
struct SmemT {
  unsigned tok;                                      // rec: barrier token (LDS)
  union {
    struct { unsigned short sW[32][1032]; } rec;     // W_hh slice, gate-interleaved rows
    struct { unsigned short A[128][72]; unsigned short Bt[256][72]; } g;
    struct { unsigned short zs[128][136]; } zst;
  } u;
  unsigned short pad_force_one_wg_per_cu[8192];      // -> ~82 KB: 1 wg/CU
};

__global__ __launch_bounds__(256, 1) void k_main(
    const int* __restrict__ x, const float* __restrict__ Wemb,
    const float* __restrict__ bih, const float* __restrict__ bhh,
    const unsigned short* __restrict__ Wihb, const unsigned short* __restrict__ Whhb,
    const unsigned short* __restrict__ wembb,
    unsigned short* __restrict__ hr, float* __restrict__ finalb,
    const int* __restrict__ tsel, const int* __restrict__ padsel,
    unsigned short* __restrict__ zxr, unsigned* __restrict__ bar, int chunkT,
    int nslot) {
  __shared__ SmemT smem;
  const int wg = blockIdx.x, tid = threadIdx.x;
  const int wave = tid >> 6, lane = tid & 63;
  const int l15 = lane & 15, lg = lane >> 4;
  unsigned* gemm_done = bar + 8384;
  unsigned* rec_done  = bar + 8448;
  const f32x4 fz = {0.f, 0.f, 0.f, 0.f};
  const int nChunks = 512 / chunkT;
  const size_t slotE = (size_t)chunkT * 64 * 4096;
  if (tid == 65535) smem.pad_force_one_wg_per_cu[0] = 0;

  if (wg < 128) {
    // ================= RECURRENT ROLE =================
    if (tid == 0) smem.tok = 0;
    // sW rows gate-interleaved: local row n<16 -> col 2*(n>>2), n>=16 -> col 2*((n-16)>>2)+1;
    // gate = n&3; global W row = gate*1024 + wg*8 + col
    for (int e = tid; e < 32 * 128; e += 256) {
      int n = e >> 7, kq = (e & 127) << 3;
      int coll = (n < 16) ? 2 * (n >> 2) : 2 * ((n - 16) >> 2) + 1;
      int grow = (n & 3) * 1024 + wg * 8 + coll;
      *(uint4*)&smem.u.rec.sW[n][kq] = *(const uint4*)(Whhb + (size_t)grow * 1024 + kq);
    }
    // lane owns (b = wave*16 + l15, cols c0 = wg*8 + 2*lg, c0+1)
    const int my_b = wave * 16 + l15;
    const int c0 = wg * 8 + 2 * lg;
    float biasv[2][4];
#pragma unroll
    for (int i = 0; i < 2; ++i)
#pragma unroll
      for (int g = 0; g < 4; ++g)
        biasv[i][g] = bih[g * 1024 + c0 + i] + bhh[g * 1024 + c0 + i];
    const int my_tsel = tsel[my_b];
    const int my_pad = padsel[my_b];
    // h store offset: element (b,k): (b>>4)*16384 + (k>>3)*128 + (b&15)*8 + (k&7)
    const size_t hwe = (size_t)wave * 16384 + (size_t)wg * 128 + (size_t)l15 * 8 + 2 * lg;
    // h load base for B-frags: k-block (ks*4+lg)*128, lane row l15*8
    const size_t hre = (size_t)wave * 16384 + (size_t)lg * 128 + (size_t)l15 * 8;
    float cc0 = 0.f, cc1 = 0.f;

    // zero h slot 0; flag=1 means "h_0 visible"
    AT_ST((unsigned*)hr + (wg * 256 + tid), 0u, __ATOMIC_RELAXED);
    __syncthreads();
    if (tid == 0) AT_ST(bar + wg * 64, 1u, __ATOMIC_RELAXED);

    for (int ch = 0; ch < nChunks; ++ch) {
      const int t0 = ch * chunkT;
      const unsigned short* zxbase = zxr + (size_t)(ch % nslot) * slotE;
      if (tid == 0) {      // wait zx chunk; ONE acquire-inv per chunk (h-ring refresh too)
        while (AT_LD(gemm_done, __ATOMIC_RELAXED) < (unsigned)(ch + 1))
          __builtin_amdgcn_s_sleep(2);
        (void)AT_LD(gemm_done, __ATOMIC_ACQUIRE);
        asm volatile("" ::: "memory");
      }
      __syncthreads();
      // zx prefetch: gate-interleaved, cols c0,c0+1 = 8 contiguous bf16 (16 B)
      union { uint4 u4; unsigned short s[8]; } vv;
      vv.u4 = *(const uint4*)(zxbase + (size_t)my_b * 4096 + c0 * 4);

      for (int tl = 0; tl < chunkT; ++tl) {
        const int t = t0 + tl;
        const unsigned need = (unsigned)t + 1u;

        // ---- 1-hop wait: wave0 polls all 128 wg-flags, others spin LDS token ----
        if (wave == 0) {
          const unsigned* f0 = bar + (lane * 2) * 64;
          const unsigned* f1 = bar + (lane * 2 + 1) * 64;
          for (;;) {
            int ok = (AT_LD(f0, __ATOMIC_RELAXED) >= need) &&
                     (AT_LD(f1, __ATOMIC_RELAXED) >= need);
            if (__all(ok)) break;
            __builtin_amdgcn_s_sleep(1);
          }
          if (lane == 0) WG_ST(&smem.tok, need);
        } else {
          while (WG_LD(&smem.tok) < need) __builtin_amdgcn_s_sleep(1);
        }
        asm volatile("" ::: "memory");

        // ---- z = W_slice @ h : A=sW (2 m-tiles of zrows), B=h (16 b), K=1024 ----
        const unsigned short* hp = hr + (size_t)(t & 15) * HSLOT + hre;
        f32x4 r0 = fz, r1 = fz;
        bf16x8 hf[32];
#pragma unroll
        for (int ks = 0; ks < 32; ++ks) hf[ks] = *(const bf16x8*)(hp + (size_t)ks * 512);
#pragma unroll
        for (int ks = 0; ks < 32; ++ks) {
          int ko = ks * 32 + (lg << 3);
          bf16x8 a0 = *(const bf16x8*)&smem.u.rec.sW[l15][ko];
          bf16x8 a1 = *(const bf16x8*)&smem.u.rec.sW[16 + l15][ko];
          r0 = MFMA16(a0, hf[ks], r0);
          r1 = MFMA16(a1, hf[ks], r1);
        }

        // ---- gates fully in-register: r0 = col c0 (i,f,g,o), r1 = col c0+1 ----
        float z00 = r0[0] + biasv[0][0] + bf2f(vv.s[0]);
        float z01 = r0[1] + biasv[0][1] + bf2f(vv.s[1]);
        float z02 = r0[2] + biasv[0][2] + bf2f(vv.s[2]);
        float z03 = r0[3] + biasv[0][3] + bf2f(vv.s[3]);
        float z10 = r1[0] + biasv[1][0] + bf2f(vv.s[4]);
        float z11 = r1[1] + biasv[1][1] + bf2f(vv.s[5]);
        float z12 = r1[2] + biasv[1][2] + bf2f(vv.s[6]);
        float z13 = r1[3] + biasv[1][3] + bf2f(vv.s[7]);

        cc0 = sigf(z01) * cc0 + sigf(z00) * tanh_(z02);
        cc1 = sigf(z11) * cc1 + sigf(z10) * tanh_(z12);
        float h0 = sigf(z03) * tanh_(cc0);
        float h1 = sigf(z13) * tanh_(cc1);

        if (t == my_tsel) {
          finalb[(size_t)my_b * 1024 + c0]     = my_pad ? 0.f : h0;
          finalb[(size_t)my_b * 1024 + c0 + 1] = my_pad ? 0.f : h1;
        }
        unsigned hp32 = (unsigned)f2bf(h0) | ((unsigned)f2bf(h1) << 16);
        AT_ST((unsigned*)(hr + (size_t)((t + 1) & 15) * HSLOT + hwe), hp32,
              __ATOMIC_RELAXED);

        if (tl + 1 < chunkT) {   // prefetch next step's zx
          vv.u4 = *(const uint4*)(zxbase + (size_t)((tl + 1) * 64 + my_b) * 4096 + c0 * 4);
        }
        __syncthreads();         // all waves' h stores drained (per-wave vmcnt + barrier)
        if (tid == 0) AT_ST(bar + wg * 64, need + 1u, __ATOMIC_RELAXED);
      }
      if (wg == 0 && tid == 0) AT_ST(rec_done, (unsigned)(ch + 1), __ATOMIC_RELAXED);
    }
  } else {
    // ============ GEMM ROLE (front-loads nslot chunks, then trickles; exits) ========
    const int gw = wg - 128;
    unsigned gt = 0;
    for (int ch = 0; ch < nChunks; ++ch) {
      if (tid == 0 && ch >= nslot) {
        while (AT_LD(rec_done, __ATOMIC_RELAXED) < (unsigned)(ch - nslot + 1))
          __builtin_amdgcn_s_sleep(8);
        asm volatile("" ::: "memory");
      }
      __syncthreads();
      const int t0 = ch * chunkT;
      unsigned short* zx = zxr + (size_t)(ch % nslot) * slotE;
      const int pmN = chunkT >> 1;
      const int npatch = pmN * 16;
      for (int p = gw; p < npatch; p += 128) {
        const int pm = p % pmN;
        const int n0 = (p / pmN) * 256;
        f32x4 acc[8][4];
#pragma unroll
        for (int mt = 0; mt < 8; ++mt)
#pragma unroll
          for (int nt = 0; nt < 4; ++nt) acc[mt][nt] = fz;
        for (int kc = 0; kc < 512; kc += 64) {
          __syncthreads();
          {
            int r = tid >> 1, half = (tid & 1) << 5;
            int tl = pm * 2 + (r >> 6), b = r & 63;
            int erow = x[b * 512 + t0 + tl];
            if (wembb) {
              const unsigned short* srcp = wembb + (size_t)erow * 512 + kc + half;
#pragma unroll
              for (int j = 0; j < 32; j += 8)
                *(uint4*)&smem.u.g.A[r][half + j] = *(const uint4*)(srcp + j);
            } else {
              const float* srcp = Wemb + (size_t)erow * 512 + kc + half;
#pragma unroll
              for (int j = 0; j < 32; j += 4) {
                float4 v = *(const float4*)(srcp + j);
                uint2 pk;
                pk.x = (unsigned)f2bf(v.x) | ((unsigned)f2bf(v.y) << 16);
                pk.y = (unsigned)f2bf(v.z) | ((unsigned)f2bf(v.w) << 16);
                *(uint2*)&smem.u.g.A[r][half + j] = pk;
              }
            }
          }
          {
            int zcx = n0 + tid;
            int wrow = (zcx & 3) * 1024 + (zcx >> 2);
            const unsigned short* srcp = Wihb + (size_t)wrow * 512 + kc;
#pragma unroll
            for (int j = 0; j < 64; j += 8)
              *(uint4*)&smem.u.g.Bt[tid][j] = *(const uint4*)(srcp + j);
          }
          __syncthreads();
#pragma unroll
          for (int ks = 0; ks < 64; ks += 32) {
            bf16x8 af[8];
#pragma unroll
            for (int mt = 0; mt < 8; ++mt)
              af[mt] = *(const bf16x8*)&smem.u.g.A[mt * 16 + l15][ks + (lg << 3)];
#pragma unroll
            for (int nt = 0; nt < 4; ++nt) {
              bf16x8 bfr =
                  *(const bf16x8*)&smem.u.g.Bt[(wave * 4 + nt) * 16 + l15][ks + (lg << 3)];
#pragma unroll
              for (int mt = 0; mt < 8; ++mt)
                acc[mt][nt] = MFMA16(af[mt], bfr, acc[mt][nt]);
            }
          }
        }
#pragma unroll
        for (int h = 0; h < 2; ++h) {
          __syncthreads();
          if ((wave >> 1) == h) {
#pragma unroll
            for (int mt = 0; mt < 8; ++mt)
#pragma unroll
              for (int nt = 0; nt < 4; ++nt)
#pragma unroll
                for (int r = 0; r < 4; ++r)
                  smem.u.zst.zs[mt * 16 + (lg << 2) + r][(wave & 1) * 64 + nt * 16 + l15] =
                      f2bf(acc[mt][nt][r]);
          }
          __syncthreads();
          int m = tid >> 1, qq = (tid & 1) << 6;
          int tl2 = pm * 2 + (m >> 6), bb = m & 63;
          unsigned short* dst = zx + ((size_t)(tl2 * 64 + bb)) * 4096 + n0 + h * 128 + qq;
#pragma unroll
          for (int j = 0; j < 64; j += 8)
            *(uint4*)(dst + j) = *(const uint4*)&smem.u.zst.zs[m][qq + j];
        }
      }
      gbar_gemm(bar, ++gt);
      if (wg == 128 && tid == 0) AT_ST(gemm_done, gt, __ATOMIC_RELAXED);
    }
  }
}

extern "C" void kernel_launch(void* const* d_in, const int* in_sizes, int n_in,
                              void* d_out, int out_size, void* d_ws, size_t ws_size,
                              hipStream_t stream) {
  (void)in_sizes; (void)n_in; (void)out_size;
  const int*   x    = (const int*)  d_in[0];
  const float* Wemb = (const float*)d_in[1];
  const float* Wih  = (const float*)d_in[2];
  const float* Whh  = (const float*)d_in[3];
  const float* bih  = (const float*)d_in[4];
  const float* bhh  = (const float*)d_in[5];
  const float* Wout = (const float*)d_in[6];
  const float* bout = (const float*)d_in[7];
  float* out = (float*)d_out;
  char* ws = (char*)d_ws;

  constexpr size_t OFF_WIH = 0;
  constexpr size_t OFF_WHH = OFF_WIH + (size_t)4096 * 512 * 2;    //  4 MB
  constexpr size_t OFF_HR  = OFF_WHH + (size_t)4096 * 1024 * 2;   // +8 MB
  constexpr size_t OFF_FIN = OFF_HR + (size_t)16 * HSLOT * 2;     // +2.06 MB
  constexpr size_t OFF_TS  = OFF_FIN + (size_t)64 * 1024 * 4;     // +256 KB
  constexpr size_t OFF_PS  = OFF_TS + 4096;
  constexpr size_t OFF_BAR = OFF_PS + 4096;
  constexpr size_t OFF_WEB = OFF_BAR + 40960;                     // 40 KB barrier zone
  constexpr size_t WEB_SZ  = (size_t)32000 * 512 * 2;             // 32 MB
  constexpr size_t SLOT_SZ = (size_t)16 * 64 * 4096 * 2;          // 8 MB per chunk slot

  int chunkT = 16;
  bool wbf = true;
  int nslot = 2;
  if (OFF_WEB + WEB_SZ + 2 * SLOT_SZ <= ws_size) {
    nslot = (int)((ws_size - OFF_WEB - WEB_SZ) / SLOT_SZ);
    if (nslot > 32) nslot = 32;
  } else if (OFF_WEB + 2 * SLOT_SZ <= ws_size) {
    wbf = false;
    nslot = (int)((ws_size - OFF_WEB) / SLOT_SZ);
    if (nslot > 32) nslot = 32;
  } else {
    wbf = false;
    while (chunkT > 2 &&
           OFF_WEB + (size_t)2 * chunkT * 64 * 4096 * 2 > ws_size)
      chunkT >>= 1;
  }
  const size_t OFF_ZX = OFF_WEB + (wbf ? WEB_SZ : 0);

  unsigned short* wihb  = (unsigned short*)(ws + OFF_WIH);
  unsigned short* whhb  = (unsigned short*)(ws + OFF_WHH);
  unsigned short* hr    = (unsigned short*)(ws + OFF_HR);
  float* finalb         = (float*)(ws + OFF_FIN);
  int* tsel             = (int*)(ws + OFF_TS);
  int* padsel           = (int*)(ws + OFF_PS);
  unsigned* bar         = (unsigned*)(ws + OFF_BAR);
  unsigned short* wembb = wbf ? (unsigned short*)(ws + OFF_WEB) : (unsigned short*)nullptr;
  unsigned short* zxr   = (unsigned short*)(ws + OFF_ZX);

  hipMemsetAsync(ws + OFF_BAR, 0, 40960, stream);
  k_conv<<<2048, 256, 0, stream>>>(Wih, Whh, Wemb, wihb, whhb, wembb);
  k_tsel<<<1, 512, 0, stream>>>(x, tsel, padsel);
  k_main<<<256, 256, 0, stream>>>(x, Wemb, bih, bhh, wihb, whhb, wembb, hr, finalb,
                                  tsel, padsel, zxr, bar, chunkT, nslot);
  k_logits<<<1, 256, 0, stream>>>(finalb, Wout, bout, out);
}

// Round 15
// 2911.186 us; speedup vs baseline: 5.2731x; 1.0842x over previous
//
#include <hip/hip_runtime.h>

typedef short bf16x8 __attribute__((ext_vector_type(8)));
typedef float f32x4  __attribute__((ext_vector_type(4)));
typedef unsigned long long u64;

#define MFMA16(a, b, c) __builtin_amdgcn_mfma_f32_16x16x32_bf16((a), (b), (c), 0, 0, 0)
#define AT_LD(p, o)    __hip_atomic_load((p), (o), __HIP_MEMORY_SCOPE_AGENT)
#define AT_ST(p, v, o) __hip_atomic_store((p), (v), (o), __HIP_MEMORY_SCOPE_AGENT)
#define AT_ADD(p, v, o) __hip_atomic_fetch_add((p), (v), (o), __HIP_MEMORY_SCOPE_AGENT)
#define WG_LD(p) __hip_atomic_load((p), __ATOMIC_ACQUIRE, __HIP_MEMORY_SCOPE_WORKGROUP)
#define WG_ST(p, v) __hip_atomic_store((p), (v), __ATOMIC_RELEASE, __HIP_MEMORY_SCOPE_WORKGROUP)

#define HSLOT 67584      // h ring slot stride in bf16 elems (128KB + 4KB pad)

// barrier zone (words): chainA flags wg*64 (0..8128); chainB flags 8192+wg*64;
// gemm cnt 16512, gemm gen 16576, gemm_done 16640, rec_doneA 16704, rec_doneB 16768
__device__ __forceinline__ unsigned short f2bf(float f) {
  union { float f; unsigned u; } v; v.f = f;
  unsigned u = v.u;
  u += 0x7fffu + ((u >> 16) & 1u);
  return (unsigned short)(u >> 16);
}
__device__ __forceinline__ float bf2f(unsigned short h) {
  union { unsigned u; float f; } v; v.u = ((unsigned)h) << 16;
  return v.f;
}
__device__ __forceinline__ float sigf(float x) { return 1.f / (1.f + __expf(-x)); }
__device__ __forceinline__ float tanh_(float x) {
  x = fminf(15.f, fmaxf(-15.f, x));
  float e = __expf(2.f * x);
  return (e - 1.f) / (e + 1.f);
}

// ---- per-chunk release barrier for the 128 GEMM wgs ----
__device__ __forceinline__ void gbar_gemm(unsigned* bar, unsigned target) {
  __syncthreads();
  if (threadIdx.x == 0) {
    unsigned arr = AT_ADD(bar + 16512, 1u, __ATOMIC_RELEASE);  // vmcnt drain + L2 wb
    if (arr == target * 128u - 1u) AT_ST(bar + 16576, target, __ATOMIC_RELEASE);
    while (AT_LD(bar + 16576, __ATOMIC_RELAXED) < target) __builtin_amdgcn_s_sleep(4);
    asm volatile("" ::: "memory");
  }
  __syncthreads();
}

// ---------------- weight conversion fp32 -> bf16 ----------------
__global__ void k_conv(const float* __restrict__ wih, const float* __restrict__ whh,
                       const float* __restrict__ wemb,
                       unsigned short* __restrict__ oih, unsigned short* __restrict__ ohh,
                       unsigned short* __restrict__ oemb) {
  const size_t NIH = (size_t)4096 * 512, NHH = (size_t)4096 * 1024;
  const size_t NE = (size_t)32000 * 512;
  size_t i0 = ((size_t)blockIdx.x * blockDim.x + threadIdx.x) * 4;
  size_t gs = (size_t)gridDim.x * blockDim.x * 4;
  for (size_t j = i0; j < NIH; j += gs) {
    float4 v = *(const float4*)(wih + j);
    uint2 pk;
    pk.x = (unsigned)f2bf(v.x) | ((unsigned)f2bf(v.y) << 16);
    pk.y = (unsigned)f2bf(v.z) | ((unsigned)f2bf(v.w) << 16);
    *(uint2*)(oih + j) = pk;
  }
  for (size_t j = i0; j < NHH; j += gs) {
    float4 v = *(const float4*)(whh + j);
    uint2 pk;
    pk.x = (unsigned)f2bf(v.x) | ((unsigned)f2bf(v.y) << 16);
    pk.y = (unsigned)f2bf(v.z) | ((unsigned)f2bf(v.w) << 16);
    *(uint2*)(ohh + j) = pk;
  }
  if (oemb)
    for (size_t j = i0; j < NE; j += gs) {
      float4 v = *(const float4*)(wemb + j);
      uint2 pk;
      pk.x = (unsigned)f2bf(v.x) | ((unsigned)f2bf(v.y) << 16);
      pk.y = (unsigned)f2bf(v.z) | ((unsigned)f2bf(v.w) << 16);
      *(uint2*)(oemb + j) = pk;
    }
}

// ---------------- lengths / selection index ----------------
__global__ void k_tsel(const int* __restrict__ x, int* __restrict__ tsel,
                       int* __restrict__ padsel) {
  int b = threadIdx.x >> 3, j = threadIdx.x & 7;
  int c = 0;
  for (int t = j * 64; t < j * 64 + 64; ++t) c += (x[b * 512 + t] != 1) ? 1 : 0;
  c += __shfl_xor(c, 1);
  c += __shfl_xor(c, 2);
  c += __shfl_xor(c, 4);
  if (j == 0) {
    int ts = (c - 1) & 511;                        // len==0 wraps to T-1
    tsel[b] = ts;
    padsel[b] = (x[b * 512 + ts] == 1) ? 1 : 0;
  }
}

// ---------------- final logits: [64,1024] @ [8,1024]^T + b ----------------
__global__ void k_logits(const float* __restrict__ finalb, const float* __restrict__ Wout,
                         const float* __restrict__ bout, float* __restrict__ out) {
  int tid = threadIdx.x;
  for (int e = tid; e < 512; e += 256) {
    int b = e >> 3, o = e & 7;
    const float* f = finalb + (size_t)b * 1024;
    const float* w = Wout + (size_t)o * 1024;
    float s = 0.f;
    for (int k = 0; k < 1024; ++k) s += f[k] * w[k];
    out[e] = s + bout[o];
  }
}

// ---------------- main kernel: 256 wgs x 512 thr = 128 rec + 128 GEMM ----------------
// Rec: dual-chain (batch halves) wave pipelining; 2 waves/SIMD hide sync latency.
struct SmemT {
  unsigned tok[2];                                   // per-chain consumer token
  unsigned cnt[2];                                   // per-chain producer counter
  union {
    struct { unsigned short sW[32][1032]; } rec;     // W_hh slice, gate-interleaved rows
    struct { unsigned short A[128][72]; unsigned short Bt[256][72]; } g;
    struct { unsigned short zs[128][136]; } zst;
  } u;
  unsigned short pad_force_one_wg_per_cu[8192];      // -> ~82 KB: 1 wg/CU
};

__global__ __launch_bounds__(512, 1) void k_main(
    const int* __restrict__ x, const float* __restrict__ Wemb,
    const float* __restrict__ bih, const float* __restrict__ bhh,
    const unsigned short* __restrict__ Wihb, const unsigned short* __restrict__ Whhb,
    const unsigned short* __restrict__ wembb,
    unsigned short* __restrict__ hr, float* __restrict__ finalb,
    const int* __restrict__ tsel, const int* __restrict__ padsel,
    unsigned short* __restrict__ zxr, unsigned* __restrict__ bar, int chunkT,
    int nslot) {
  __shared__ SmemT smem;
  const int wg = blockIdx.x, tid = threadIdx.x;
  const int wave = tid >> 6, lane = tid & 63;
  const int l15 = lane & 15, lg = lane >> 4;
  unsigned* gemm_done = bar + 16640;
  const f32x4 fz = {0.f, 0.f, 0.f, 0.f};
  const int nChunks = 512 / chunkT;
  const size_t slotE = (size_t)chunkT * 64 * 4096;
  if (tid == 65535) smem.pad_force_one_wg_per_cu[0] = 0;

  if (wg < 128) {
    // ================= RECURRENT ROLE: dual chains =================
    const int chain = wave >> 2;        // 0: b 0..31, 1: b 32..63
    const int wv = wave & 3;            // role within chain
    const int btile = chain * 2 + (wv >> 1);
    const int mtile = wv & 1;
    const int my_b = btile * 16 + l15;
    const int col_local = 2 * lg + mtile;
    const int cg = wg * 8 + col_local;  // global h column
    unsigned* myflags = bar + chain * 8192;
    unsigned* recdone = bar + 16704 + chain * 64;

    if (tid == 0) { smem.tok[0] = 0; smem.tok[1] = 0; smem.cnt[0] = 0; smem.cnt[1] = 0; }
    // sW fill (512 threads): rows gate-interleaved as R14
    for (int e = tid; e < 32 * 64; e += 512) {
      int n = e >> 6, kq = (e & 63) << 4;
      int coll = (n < 16) ? 2 * (n >> 2) : 2 * ((n - 16) >> 2) + 1;
      int grow = (n & 3) * 1024 + wg * 8 + coll;
      *(uint4*)&smem.u.rec.sW[n][kq] = *(const uint4*)(Whhb + (size_t)grow * 1024 + kq);
      *(uint4*)&smem.u.rec.sW[n][kq + 8] =
          *(const uint4*)(Whhb + (size_t)grow * 1024 + kq + 8);
    }
    float biasv[4];
#pragma unroll
    for (int g = 0; g < 4; ++g) biasv[g] = bih[g * 1024 + cg] + bhh[g * 1024 + cg];
    const int my_tsel = tsel[my_b];
    const int my_pad = padsel[my_b];
    const size_t hwe = (size_t)btile * 16384 + (size_t)wg * 128 + (size_t)l15 * 8 + col_local;
    const size_t hre = (size_t)btile * 16384 + (size_t)lg * 128 + (size_t)l15 * 8;
    float cc = 0.f;

    // zero h slot 0 (128 KB total across wgs)
    {
      int e = wg * 512 + tid;
      if (e < 32768) AT_ST((unsigned*)hr + e, 0u, __ATOMIC_RELAXED);
    }
    __syncthreads();                    // drains all waves' stores; last wg-wide sync
    if (wv == 0 && lane == 0) AT_ST(myflags + wg * 64, 1u, __ATOMIC_RELAXED);

    for (int ch = 0; ch < nChunks; ++ch) {
      const int t0 = ch * chunkT;
      const unsigned short* zxbase = zxr + (size_t)(ch % nslot) * slotE;
      union { uint2 u2; unsigned short s[4]; } vv;
      bool vvload = true;               // load zx for tl=0 after chunk gate

      for (int tl = 0; tl < chunkT; ++tl) {
        const int t = t0 + tl;
        const unsigned need = (unsigned)t + 1u;

        if (wv == 0) {                  // chain poller wave
          if (tl == 0) {
            if (lane == 0) {
              while (AT_LD(gemm_done, __ATOMIC_RELAXED) < (unsigned)(ch + 1))
                __builtin_amdgcn_s_sleep(2);
              (void)AT_LD(gemm_done, __ATOMIC_ACQUIRE);   // inv: fresh zx + h-ring
              asm volatile("" ::: "memory");
            }
          }
          const unsigned* f0 = myflags + (lane * 2) * 64;
          const unsigned* f1 = myflags + (lane * 2 + 1) * 64;
          for (;;) {
            int ok = (AT_LD(f0, __ATOMIC_RELAXED) >= need) &&
                     (AT_LD(f1, __ATOMIC_RELAXED) >= need);
            if (__all(ok)) break;
            __builtin_amdgcn_s_sleep(1);
          }
          if (lane == 0) WG_ST(&smem.tok[chain], need);
        } else {
          while (WG_LD(&smem.tok[chain]) < need) __builtin_amdgcn_s_sleep(1);
        }
        asm volatile("" ::: "memory");

        if (vvload) {                   // zx for this step (post-acquire)
          vv.u2 = *(const uint2*)(zxbase + (size_t)(tl * 64 + my_b) * 4096 + cg * 4);
          vvload = false;
        }

        // ---- z = W_mtile @ h_btile : 32 MFMAs, K=1024 ----
        const unsigned short* hp = hr + (size_t)(t & 15) * HSLOT + hre;
        f32x4 r0 = fz;
        bf16x8 hf[32];
#pragma unroll
        for (int ks = 0; ks < 32; ++ks) hf[ks] = *(const bf16x8*)(hp + (size_t)ks * 512);
#pragma unroll
        for (int ks = 0; ks < 32; ++ks) {
          bf16x8 a0 = *(const bf16x8*)&smem.u.rec.sW[mtile * 16 + l15][ks * 32 + (lg << 3)];
          r0 = MFMA16(a0, hf[ks], r0);
        }

        // ---- gates lane-local: r0 = (i,f,g,o) for (my_b, cg) ----
        float z0 = r0[0] + biasv[0] + bf2f(vv.s[0]);
        float z1 = r0[1] + biasv[1] + bf2f(vv.s[1]);
        float z2 = r0[2] + biasv[2] + bf2f(vv.s[2]);
        float z3 = r0[3] + biasv[3] + bf2f(vv.s[3]);
        cc = sigf(z1) * cc + sigf(z0) * tanh_(z2);
        float h = sigf(z3) * tanh_(cc);

        if (t == my_tsel) finalb[(size_t)my_b * 1024 + cg] = my_pad ? 0.f : h;
        __hip_atomic_store(hr + (size_t)((t + 1) & 15) * HSLOT + hwe, f2bf(h),
                           __ATOMIC_RELAXED, __HIP_MEMORY_SCOPE_AGENT);

        if (tl + 1 < chunkT) {          // prefetch next step's zx
          vv.u2 = *(const uint2*)(zxbase + (size_t)((tl + 1) * 64 + my_b) * 4096 + cg * 4);
        }
        asm volatile("s_waitcnt vmcnt(0)" ::: "memory");   // h store (+ zx pf) ack'd
        if (lane == 0)
          __hip_atomic_fetch_add(&smem.cnt[chain], 1u, __ATOMIC_ACQ_REL,
                                 __HIP_MEMORY_SCOPE_WORKGROUP);
        if (wv == 0 && lane == 0) {
          while (__hip_atomic_load(&smem.cnt[chain], __ATOMIC_ACQUIRE,
                                   __HIP_MEMORY_SCOPE_WORKGROUP) < 4u * need)
            __builtin_amdgcn_s_sleep(1);
          AT_ST(myflags + wg * 64, need + 1u, __ATOMIC_RELAXED);
        }
      }
      if (wv == 0 && lane == 0) AT_ST(recdone, (unsigned)(ch + 1), __ATOMIC_RELAXED);
    }
  } else {
    // ============ GEMM ROLE (512 thr; tid&255 duplication — benign) ============
    const int gw = wg - 128;
    const int t2 = tid & 255;
    const int wv4 = (tid >> 6) & 3;
    unsigned* rdA = bar + 16704;
    unsigned* rdB = bar + 16768;
    unsigned gt = 0;
    for (int ch = 0; ch < nChunks; ++ch) {
      if (tid == 0 && ch >= nslot) {
        unsigned tgt = (unsigned)(ch - nslot + 1);
        for (;;) {
          unsigned a = AT_LD(rdA, __ATOMIC_RELAXED), b = AT_LD(rdB, __ATOMIC_RELAXED);
          if (a >= tgt && b >= tgt) break;
          __builtin_amdgcn_s_sleep(8);
        }
        asm volatile("" ::: "memory");
      }
      __syncthreads();
      const int t0 = ch * chunkT;
      unsigned short* zx = zxr + (size_t)(ch % nslot) * slotE;
      const int pmN = chunkT >> 1;
      const int npatch = pmN * 16;
      for (int p = gw; p < npatch; p += 128) {
        const int pm = p % pmN;
        const int n0 = (p / pmN) * 256;
        f32x4 acc[8][4];
#pragma unroll
        for (int mt = 0; mt < 8; ++mt)
#pragma unroll
          for (int nt = 0; nt < 4; ++nt) acc[mt][nt] = fz;
        for (int kc = 0; kc < 512; kc += 64) {
          __syncthreads();
          {
            int r = t2 >> 1, half = (t2 & 1) << 5;
            int tl = pm * 2 + (r >> 6), b = r & 63;
            int erow = x[b * 512 + t0 + tl];
            if (wembb) {
              const unsigned short* srcp = wembb + (size_t)erow * 512 + kc + half;
#pragma unroll
              for (int j = 0; j < 32; j += 8)
                *(uint4*)&smem.u.g.A[r][half + j] = *(const uint4*)(srcp + j);
            } else {
              const float* srcp = Wemb + (size_t)erow * 512 + kc + half;
#pragma unroll
              for (int j = 0; j < 32; j += 4) {
                float4 v = *(const float4*)(srcp + j);
                uint2 pk;
                pk.x = (unsigned)f2bf(v.x) | ((unsigned)f2bf(v.y) << 16);
                pk.y = (unsigned)f2bf(v.z) | ((unsigned)f2bf(v.w) << 16);
                *(uint2*)&smem.u.g.A[r][half + j] = pk;
              }
            }
          }
          {
            int zcx = n0 + t2;
            int wrow = (zcx & 3) * 1024 + (zcx >> 2);
            const unsigned short* srcp = Wihb + (size_t)wrow * 512 + kc;
#pragma unroll
            for (int j = 0; j < 64; j += 8)
              *(uint4*)&smem.u.g.Bt[t2][j] = *(const uint4*)(srcp + j);
          }
          __syncthreads();
#pragma unroll
          for (int ks = 0; ks < 64; ks += 32) {
            bf16x8 af[8];
#pragma unroll
            for (int mt = 0; mt < 8; ++mt)
              af[mt] = *(const bf16x8*)&smem.u.g.A[mt * 16 + l15][ks + (lg << 3)];
#pragma unroll
            for (int nt = 0; nt < 4; ++nt) {
              bf16x8 bfr =
                  *(const bf16x8*)&smem.u.g.Bt[(wv4 * 4 + nt) * 16 + l15][ks + (lg << 3)];
#pragma unroll
              for (int mt = 0; mt < 8; ++mt)
                acc[mt][nt] = MFMA16(af[mt], bfr, acc[mt][nt]);
            }
          }
        }
#pragma unroll
        for (int h = 0; h < 2; ++h) {
          __syncthreads();
          if ((wv4 >> 1) == h) {
#pragma unroll
            for (int mt = 0; mt < 8; ++mt)
#pragma unroll
              for (int nt = 0; nt < 4; ++nt)
#pragma unroll
                for (int r = 0; r < 4; ++r)
                  smem.u.zst.zs[mt * 16 + (lg << 2) + r][(wv4 & 1) * 64 + nt * 16 + l15] =
                      f2bf(acc[mt][nt][r]);
          }
          __syncthreads();
          int m = t2 >> 1, qq = (t2 & 1) << 6;
          int tl2 = pm * 2 + (m >> 6), bb = m & 63;
          unsigned short* dst = zx + ((size_t)(tl2 * 64 + bb)) * 4096 + n0 + h * 128 + qq;
#pragma unroll
          for (int j = 0; j < 64; j += 8)
            *(uint4*)(dst + j) = *(const uint4*)&smem.u.zst.zs[m][qq + j];
        }
      }
      gbar_gemm(bar, ++gt);
      if (wg == 128 && tid == 0) AT_ST(gemm_done, gt, __ATOMIC_RELAXED);
    }
  }
}

extern "C" void kernel_launch(void* const* d_in, const int* in_sizes, int n_in,
                              void* d_out, int out_size, void* d_ws, size_t ws_size,
                              hipStream_t stream) {
  (void)in_sizes; (void)n_in; (void)out_size;
  const int*   x    = (const int*)  d_in[0];
  const float* Wemb = (const float*)d_in[1];
  const float* Wih  = (const float*)d_in[2];
  const float* Whh  = (const float*)d_in[3];
  const float* bih  = (const float*)d_in[4];
  const float* bhh  = (const float*)d_in[5];
  const float* Wout = (const float*)d_in[6];
  const float* bout = (const float*)d_in[7];
  float* out = (float*)d_out;
  char* ws = (char*)d_ws;

  constexpr size_t OFF_WIH = 0;
  constexpr size_t OFF_WHH = OFF_WIH + (size_t)4096 * 512 * 2;    //  4 MB
  constexpr size_t OFF_HR  = OFF_WHH + (size_t)4096 * 1024 * 2;   // +8 MB
  constexpr size_t OFF_FIN = OFF_HR + (size_t)16 * HSLOT * 2;     // +2.06 MB
  constexpr size_t OFF_TS  = OFF_FIN + (size_t)64 * 1024 * 4;     // +256 KB
  constexpr size_t OFF_PS  = OFF_TS + 4096;
  constexpr size_t OFF_BAR = OFF_PS + 4096;
  constexpr size_t OFF_WEB = OFF_BAR + 73728;                     // 72 KB barrier zone
  constexpr size_t WEB_SZ  = (size_t)32000 * 512 * 2;             // 32 MB
  constexpr size_t SLOT_SZ = (size_t)16 * 64 * 4096 * 2;          // 8 MB per chunk slot

  int chunkT = 16;
  bool wbf = true;
  int nslot = 2;
  if (OFF_WEB + WEB_SZ + 2 * SLOT_SZ <= ws_size) {
    nslot = (int)((ws_size - OFF_WEB - WEB_SZ) / SLOT_SZ);
    if (nslot > 32) nslot = 32;
  } else if (OFF_WEB + 2 * SLOT_SZ <= ws_size) {
    wbf = false;
    nslot = (int)((ws_size - OFF_WEB) / SLOT_SZ);
    if (nslot > 32) nslot = 32;
  } else {
    wbf = false;
    while (chunkT > 2 &&
           OFF_WEB + (size_t)2 * chunkT * 64 * 4096 * 2 > ws_size)
      chunkT >>= 1;
  }
  const size_t OFF_ZX = OFF_WEB + (wbf ? WEB_SZ : 0);

  unsigned short* wihb  = (unsigned short*)(ws + OFF_WIH);
  unsigned short* whhb  = (unsigned short*)(ws + OFF_WHH);
  unsigned short* hr    = (unsigned short*)(ws + OFF_HR);
  float* finalb         = (float*)(ws + OFF_FIN);
  int* tsel             = (int*)(ws + OFF_TS);
  int* padsel           = (int*)(ws + OFF_PS);
  unsigned* bar         = (unsigned*)(ws + OFF_BAR);
  unsigned short* wembb = wbf ? (unsigned short*)(ws + OFF_WEB) : (unsigned short*)nullptr;
  unsigned short* zxr   = (unsigned short*)(ws + OFF_ZX);

  hipMemsetAsync(ws + OFF_BAR, 0, 73728, stream);
  k_conv<<<2048, 256, 0, stream>>>(Wih, Whh, Wemb, wihb, whhb, wembb);
  k_tsel<<<1, 512, 0, stream>>>(x, tsel, padsel);
  k_main<<<256, 512, 0, stream>>>(x, Wemb, bih, bhh, wihb, whhb, wembb, hr, finalb,
                                  tsel, padsel, zxr, bar, chunkT, nslot);
  k_logits<<<1, 256, 0, stream>>>(finalb, Wout, bout, out);
}